// Round 6
// baseline (113.884 us; speedup 1.0000x reference)
//
#include <hip/hip_runtime.h>
#include <math.h>

#define NLM   1024      // landmarks per batch
#define NB    2         // batches
#define OPS   40        // coarse grid size per axis
#define DIM   128       // output volume size per axis
#define OPS3  (OPS*OPS*OPS)
#define DIM3  (DIM*DIM*DIM)

// coarse tile: 4(p) x 4(q) x 8(r) cells = 128 cells, 1 cell/thread
#define P_T 4
#define Q_T 4
#define R_T 8
#define NP  (OPS/P_T)    // 10
#define NQ  (OPS/Q_T)    // 10
#define NR  (OPS/R_T)    // 5
#define MARGIN 0.30f     // exp2(-288.5*0.09) ~ 2e-8 -> negligible truncation

// exp(-d2/ALPHA) = exp2(K2*d2), K2 = -1/(ALPHA*ln2); M2 = -2*K2
#define K2f  (-288.5390081777927f)
#define M2f  ( 577.0780163555854f)

// ws layout: coarse : float4[NB*OPS3] @ 0   (2,048,000 bytes)

__device__ __forceinline__ float fexp2(float x) {
#if __has_builtin(__builtin_amdgcn_exp2f)
    return __builtin_amdgcn_exp2f(x);
#else
    return exp2f(x);
#endif
}

// One block per 4x4x8 coarse tile (500 tiles x 2 batches), 128 threads.
// Phase 1: compact landmarks in the tile's +-MARGIN box into LDS (~70 avg).
// Phase 2: 1 cell per thread over the compacted list.
__global__ __launch_bounds__(128)
void coarse_kernel(const float* __restrict__ coords, const float* __restrict__ offs,
                   float4* __restrict__ C) {
    __shared__ float4 sA[NLM];       // worst-case safety
    __shared__ float4 sV[NLM];
    __shared__ int sCnt;

    const int t = threadIdx.x;       // 0..127
    const int b = blockIdx.y;
    const int tile = blockIdx.x;     // 0..499
    const int tp = tile / (NQ*NR);
    const int tq = (tile / NR) % NQ;
    const int tr = tile % NR;

    const float step = 2.f / (OPS - 1);
    const float bx0 = -1.f + step * (tr*R_T)          - MARGIN;   // component 0 (r)
    const float bx1 = -1.f + step * (tr*R_T + R_T-1)  + MARGIN;
    const float by0 = -1.f + step * (tq*Q_T)          - MARGIN;   // component 1 (q)
    const float by1 = -1.f + step * (tq*Q_T + Q_T-1)  + MARGIN;
    const float bz0 = -1.f + step * (tp*P_T)          - MARGIN;   // component 2 (p)
    const float bz1 = -1.f + step * (tp*P_T + P_T-1)  + MARGIN;

    if (t == 0) sCnt = 0;
    __syncthreads();

    for (int n = t; n < NLM; n += 128) {
        const float* cp = coords + (b*NLM + n)*3;
        const float* op = offs   + (b*NLM + n)*3;
        float ox = op[0], oy = op[1], oz = op[2];
        float cx = cp[0] + ox, cy = cp[1] + oy, cz = cp[2] + oz;
        if (cx >= bx0 && cx <= bx1 && cy >= by0 && cy <= by1 &&
            cz >= bz0 && cz <= bz1) {
            int idx = atomicAdd(&sCnt, 1);
            sA[idx] = make_float4(cx, cy, cz, K2f*(cx*cx + cy*cy + cz*cz));
            sV[idx] = make_float4(-ox, -oy, -oz, 0.f);
        }
    }
    __syncthreads();
    const int cnt = sCnt;

    const int lp = t >> 5;           // 0..3
    const int lq = (t >> 3) & 3;     // 0..3
    const int lr = t & 7;            // 0..7
    const float gx = -1.f + step * (tr*R_T + lr);
    const float gy = -1.f + step * (tq*Q_T + lq);
    const float gz = -1.f + step * (tp*P_T + lp);
    const float h  = K2f * (gx*gx + gy*gy + gz*gz);

    float aS = 0.f, aX = 0.f, aY = 0.f, aZ = 0.f;
    for (int n = 0; n < cnt; ++n) {
        float4 a = sA[n];            // LDS broadcast
        float4 v = sV[n];
        float u   = fmaf(gx, a.x, fmaf(gy, a.y, gz*a.z));
        float arg = fmaf(M2f, u, h + a.w);   // K2*||g-c||^2
        float e   = fexp2(arg);
        aS += e;
        aX = fmaf(e, v.x, aX);
        aY = fmaf(e, v.y, aY);
        aZ = fmaf(e, v.z, aZ);
    }

    const int p = tp*P_T + lp, q = tq*Q_T + lq, r = tr*R_T + lr;
    const float inv = 1.01f / (aS + 0.01f);  // (BETA+1)/(sum+BETA)
    C[b*OPS3 + (p*OPS + q)*OPS + r] = make_float4(aX*inv, aY*inv, aZ*inv, 0.f);
}

__device__ __forceinline__ void axis_interp(int t, int& a0, int& a1, float& w) {
    float c = fmaxf(0.3125f * (float)t - 0.34375f, 0.f);
    float f = floorf(c);
    a0 = (int)f;
    a1 = min(a0 + 1, OPS - 1);
    w = c - f;
}

__device__ __forceinline__ float4 lerp4(float4 a, float4 b, float t) {
    return make_float4(a.x + t*(b.x - a.x),
                       a.y + t*(b.y - a.y),
                       a.z + t*(b.z - a.z),
                       0.f);
}

// 256-thread blocks, 8 k-lines per block (wave w -> lines 2w, 2w+1), 4
// voxels/thread, branch-free zero-padding gather (per-axis masked weights;
// AND-wrapped indices are safe because the wrapped tap's weight is 0).
// XCD slab swizzle: slot g&7 owns a contiguous 32-i slab.
__global__ __launch_bounds__(256)
void warp_kernel(const float* __restrict__ mask, const float4* __restrict__ C,
                 float* __restrict__ out) {
    __shared__ float4 sF[8][OPS];    // 8 lines x 40 float4 = 5 KB

    const int g = blockIdx.x;                        // 0..4095
    const int w = threadIdx.x >> 6;                  // wave 0..3
    const int lane = threadIdx.x & 63;
    const int line0 = ((g & 7) << 12) + ((g >> 3) << 3) + (w << 1);

    const float s127 = 2.f / (DIM - 1);

    // per-wave sF fill for its two lines (no barrier: wave-private slices)
    #pragma unroll
    for (int e = 0; e < 2; ++e) {
        const int line = line0 + e;
        const int j = line & (DIM-1);
        const int i = (line >> 7) & (DIM-1);
        const int b = line >> 14;
        int i0,i1,j0,j1; float ti,tj;
        axis_interp(i, i0, i1, ti);
        axis_interp(j, j0, j1, tj);
        const float4* Cb = C + b*OPS3;
        if (lane < OPS) {
            float4 c00 = Cb[(i0*OPS + j0)*OPS + lane];
            float4 c01 = Cb[(i0*OPS + j1)*OPS + lane];
            float4 c10 = Cb[(i1*OPS + j0)*OPS + lane];
            float4 c11 = Cb[(i1*OPS + j1)*OPS + lane];
            sF[(w<<1)+e][lane] = lerp4(lerp4(c00, c01, tj), lerp4(c10, c11, tj), ti);
        }
    }

    // phase A: addresses + masked weights for 4 voxels
    int   off[4][6];
    float wt[4][6];
    int   oidx[4];
    const float* Mv[4];
    #pragma unroll
    for (int e = 0; e < 2; ++e) {
        const int line = line0 + e;
        const int j = line & (DIM-1);
        const int i = (line >> 7) & (DIM-1);
        const int b = line >> 14;
        const float yb = -1.f + s127 * (float)j;
        const float zb = -1.f + s127 * (float)i;
        const float* M = mask + b * DIM3;
        #pragma unroll
        for (int c = 0; c < 2; ++c) {
            const int vi = e*2 + c;
            const int k = lane + (c << 6);
            int k0,k1; float tk;
            axis_interp(k, k0, k1, tk);
            float4 fl = lerp4(sF[(w<<1)+e][k0], sF[(w<<1)+e][k1], tk);

            float x = -1.f + s127 * (float)k + fl.x;
            float y = yb + fl.y;
            float z = zb + fl.z;
            float px = ((x + 1.f) * (float)DIM - 1.f) * 0.5f;
            float py = ((y + 1.f) * (float)DIM - 1.f) * 0.5f;
            float pz = ((z + 1.f) * (float)DIM - 1.f) * 0.5f;

            float xf = floorf(px), yf = floorf(py), zf = floorf(pz);
            float ax = px - xf,    ay = py - yf,    az = pz - zf;
            int x0 = (int)xf, y0 = (int)yf, z0 = (int)zf;

            wt[vi][0] = ((unsigned)x0     < 128u) ? (1.f - ax) : 0.f;
            wt[vi][1] = ((unsigned)(x0+1) < 128u) ? ax         : 0.f;
            wt[vi][2] = ((unsigned)y0     < 128u) ? (1.f - ay) : 0.f;
            wt[vi][3] = ((unsigned)(y0+1) < 128u) ? ay         : 0.f;
            wt[vi][4] = ((unsigned)z0     < 128u) ? (1.f - az) : 0.f;
            wt[vi][5] = ((unsigned)(z0+1) < 128u) ? az         : 0.f;

            off[vi][0] = (x0 & 127);
            off[vi][1] = ((x0+1) & 127);
            off[vi][2] = (y0 & 127) << 7;
            off[vi][3] = ((y0+1) & 127) << 7;
            off[vi][4] = (z0 & 127) << 14;
            off[vi][5] = ((z0+1) & 127) << 14;
            Mv[vi]   = M;
            oidx[vi] = (line << 7) + k;
        }
    }

    // phase B: all 32 taps issued before any accumulation
    float tv[4][8];
    #pragma unroll
    for (int vi = 0; vi < 4; ++vi) {
        const float* M = Mv[vi];
        const int xa = off[vi][0], xb = off[vi][1];
        const int ya = off[vi][2], yc = off[vi][3];
        const int za = off[vi][4], zc = off[vi][5];
        tv[vi][0] = M[za + ya + xa];
        tv[vi][1] = M[za + ya + xb];
        tv[vi][2] = M[za + yc + xa];
        tv[vi][3] = M[za + yc + xb];
        tv[vi][4] = M[zc + ya + xa];
        tv[vi][5] = M[zc + ya + xb];
        tv[vi][6] = M[zc + yc + xa];
        tv[vi][7] = M[zc + yc + xb];
    }

    // phase C: accumulate + store
    #pragma unroll
    for (int vi = 0; vi < 4; ++vi) {
        float wx0 = wt[vi][0], wx1 = wt[vi][1];
        float wy0 = wt[vi][2], wy1 = wt[vi][3];
        float wz0 = wt[vi][4], wz1 = wt[vi][5];
        float w00 = wz0*wy0, w01 = wz0*wy1, w10 = wz1*wy0, w11 = wz1*wy1;
        float r;
        r = tv[vi][0] * (w00*wx0);
        r = fmaf(tv[vi][1], w00*wx1, r);
        r = fmaf(tv[vi][2], w01*wx0, r);
        r = fmaf(tv[vi][3], w01*wx1, r);
        r = fmaf(tv[vi][4], w10*wx0, r);
        r = fmaf(tv[vi][5], w10*wx1, r);
        r = fmaf(tv[vi][6], w11*wx0, r);
        r = fmaf(tv[vi][7], w11*wx1, r);
        out[oidx[vi]] = r;
    }
}

extern "C" void kernel_launch(void* const* d_in, const int* in_sizes, int n_in,
                              void* d_out, int out_size, void* d_ws, size_t ws_size,
                              hipStream_t stream) {
    const float* mask   = (const float*)d_in[0];   // (2,1,128,128,128)
    const float* coords = (const float*)d_in[1];   // (2,1024,3)
    const float* offs   = (const float*)d_in[2];   // (2,1024,3)
    float* out = (float*)d_out;

    float4* coarse = (float4*)d_ws;                // NB*OPS3 float4

    dim3 g1(NP*NQ*NR, NB);                         // 500 x 2 blocks
    coarse_kernel<<<g1, 128, 0, stream>>>(coords, offs, coarse);

    warp_kernel<<<NB*DIM*DIM/8, 256, 0, stream>>>(mask, coarse, out);
}

// Round 7
// 112.639 us; speedup vs baseline: 1.0111x; 1.0111x over previous
//
#include <hip/hip_runtime.h>
#include <math.h>

#define NLM   1024      // landmarks per batch
#define NB    2         // batches
#define OPS   40        // coarse grid size per axis
#define DIM   128       // output volume size per axis
#define OPS3  (OPS*OPS*OPS)
#define DIM3  (DIM*DIM*DIM)

// coarse tile: 4(p) x 4(q) x 8(r) cells = 128 cells, 1 cell/thread
#define P_T 4
#define Q_T 4
#define R_T 8
#define NP  (OPS/P_T)    // 10
#define NQ  (OPS/Q_T)    // 10
#define NR  (OPS/R_T)    // 5
#define MARGIN 0.30f     // exp2(-288.5*0.09) ~ 2e-8 -> negligible truncation

// exp(-d2/ALPHA) = exp2(K2*d2), K2 = -1/(ALPHA*ln2); M2 = -2*K2
#define K2f  (-288.5390081777927f)
#define M2f  ( 577.0780163555854f)

// ws layout: coarse : float4[NB*OPS3] @ 0   (2,048,000 bytes)

__device__ __forceinline__ float fexp2(float x) {
#if __has_builtin(__builtin_amdgcn_exp2f)
    return __builtin_amdgcn_exp2f(x);
#else
    return exp2f(x);
#endif
}

// One block per 4x4x8 coarse tile (500 tiles x 2 batches), 128 threads.
__global__ __launch_bounds__(128)
void coarse_kernel(const float* __restrict__ coords, const float* __restrict__ offs,
                   float4* __restrict__ C) {
    __shared__ float4 sA[NLM];
    __shared__ float4 sV[NLM];
    __shared__ int sCnt;

    const int t = threadIdx.x;       // 0..127
    const int b = blockIdx.y;
    const int tile = blockIdx.x;     // 0..499
    const int tp = tile / (NQ*NR);
    const int tq = (tile / NR) % NQ;
    const int tr = tile % NR;

    const float step = 2.f / (OPS - 1);
    const float bx0 = -1.f + step * (tr*R_T)          - MARGIN;
    const float bx1 = -1.f + step * (tr*R_T + R_T-1)  + MARGIN;
    const float by0 = -1.f + step * (tq*Q_T)          - MARGIN;
    const float by1 = -1.f + step * (tq*Q_T + Q_T-1)  + MARGIN;
    const float bz0 = -1.f + step * (tp*P_T)          - MARGIN;
    const float bz1 = -1.f + step * (tp*P_T + P_T-1)  + MARGIN;

    if (t == 0) sCnt = 0;
    __syncthreads();

    for (int n = t; n < NLM; n += 128) {
        const float* cp = coords + (b*NLM + n)*3;
        const float* op = offs   + (b*NLM + n)*3;
        float ox = op[0], oy = op[1], oz = op[2];
        float cx = cp[0] + ox, cy = cp[1] + oy, cz = cp[2] + oz;
        if (cx >= bx0 && cx <= bx1 && cy >= by0 && cy <= by1 &&
            cz >= bz0 && cz <= bz1) {
            int idx = atomicAdd(&sCnt, 1);
            sA[idx] = make_float4(cx, cy, cz, K2f*(cx*cx + cy*cy + cz*cz));
            sV[idx] = make_float4(-ox, -oy, -oz, 0.f);
        }
    }
    __syncthreads();
    const int cnt = sCnt;

    const int lp = t >> 5;
    const int lq = (t >> 3) & 3;
    const int lr = t & 7;
    const float gx = -1.f + step * (tr*R_T + lr);
    const float gy = -1.f + step * (tq*Q_T + lq);
    const float gz = -1.f + step * (tp*P_T + lp);
    const float h  = K2f * (gx*gx + gy*gy + gz*gz);

    float aS = 0.f, aX = 0.f, aY = 0.f, aZ = 0.f;
    for (int n = 0; n < cnt; ++n) {
        float4 a = sA[n];            // LDS broadcast
        float4 v = sV[n];
        float u   = fmaf(gx, a.x, fmaf(gy, a.y, gz*a.z));
        float arg = fmaf(M2f, u, h + a.w);   // K2*||g-c||^2
        float e   = fexp2(arg);
        aS += e;
        aX = fmaf(e, v.x, aX);
        aY = fmaf(e, v.y, aY);
        aZ = fmaf(e, v.z, aZ);
    }

    const int p = tp*P_T + lp, q = tq*Q_T + lq, r = tr*R_T + lr;
    const float inv = 1.01f / (aS + 0.01f);
    C[b*OPS3 + (p*OPS + q)*OPS + r] = make_float4(aX*inv, aY*inv, aZ*inv, 0.f);
}

__device__ __forceinline__ void axis_interp(int t, int& a0, int& a1, float& w) {
    float c = fmaxf(0.3125f * (float)t - 0.34375f, 0.f);
    float f = floorf(c);
    a0 = (int)f;
    a1 = min(a0 + 1, OPS - 1);
    w = c - f;
}

__device__ __forceinline__ float4 lerp4(float4 a, float4 b, float t) {
    return make_float4(a.x + t*(b.x - a.x),
                       a.y + t*(b.y - a.y),
                       a.z + t*(b.z - a.z),
                       0.f);
}

// Per-voxel branch-free address/weight set. Wrapped (&127) indices are safe
// because the corresponding masked weight is 0; max index = DIM3-1.
struct AW {
    int r0, r1, r2, r3;     // 4 row bases (z,y combinations)
    int xa, xb;             // 2 x offsets
    float wx0, wx1, wy0, wy1, wz0, wz1;
};

__device__ __forceinline__ AW make_aw(float px, float py, float pz) {
    AW s;
    float xf = floorf(px), yf = floorf(py), zf = floorf(pz);
    int x0 = (int)xf, y0 = (int)yf, z0 = (int)zf;
    float ax = px - xf, ay = py - yf, az = pz - zf;

    s.wx0 = ((unsigned)x0     < 128u) ? (1.f - ax) : 0.f;
    s.wx1 = ((unsigned)(x0+1) < 128u) ? ax         : 0.f;
    s.wy0 = ((unsigned)y0     < 128u) ? (1.f - ay) : 0.f;
    s.wy1 = ((unsigned)(y0+1) < 128u) ? ay         : 0.f;
    s.wz0 = ((unsigned)z0     < 128u) ? (1.f - az) : 0.f;
    s.wz1 = ((unsigned)(z0+1) < 128u) ? az         : 0.f;

    int ya = (y0 & 127) << 7, yb2 = ((y0+1) & 127) << 7;
    int za = (z0 & 127) << 14, zb2 = ((z0+1) & 127) << 14;
    s.xa = x0 & 127;
    s.xb = (x0+1) & 127;
    s.r0 = za + ya;  s.r1 = za + yb2;
    s.r2 = zb2 + ya; s.r3 = zb2 + yb2;
    return s;
}

// 256-thread blocks = 4 waves; wave w handles line line0+w; each lane 2
// voxels (k=lane, k=lane+64). Branch-free zero-pad gather; both voxels'
// 16 taps issued before accumulation. XCD slab swizzle: slot g&7 owns a
// contiguous i-slab (coarse z-plane locality in the per-XCD L2).
__global__ __launch_bounds__(256)
void warp_kernel(const float* __restrict__ mask, const float4* __restrict__ C,
                 float* __restrict__ out) {
    __shared__ float4 sF[4][OPS];    // per-wave k-line flow

    const int g = blockIdx.x;                        // 0..8191
    const int w = threadIdx.x >> 6;                  // wave 0..3
    const int lane = threadIdx.x & 63;
    const int line = ((g & 7) << 12) + ((g >> 3) << 2) + w;  // b*DIM^2+i*DIM+j
    const int j = line & (DIM-1);
    const int i = (line >> 7) & (DIM-1);
    const int b = line >> 14;

    int i0,i1,j0,j1; float ti,tj;
    axis_interp(i, i0, i1, ti);
    axis_interp(j, j0, j1, tj);

    const float4* Cb = C + b*OPS3;
    if (lane < OPS) {
        float4 c00 = Cb[(i0*OPS + j0)*OPS + lane];
        float4 c01 = Cb[(i0*OPS + j1)*OPS + lane];
        float4 c10 = Cb[(i1*OPS + j0)*OPS + lane];
        float4 c11 = Cb[(i1*OPS + j1)*OPS + lane];
        sF[w][lane] = lerp4(lerp4(c00, c01, tj), lerp4(c10, c11, tj), ti);
    }
    // no barrier: sF[w] is wave-private (produced & consumed in lockstep)

    const float* M = mask + b * DIM3;
    const float s127 = 2.f / (DIM - 1);
    const float yb = -1.f + s127 * (float)j;
    const float zb = -1.f + s127 * (float)i;

    // phase A: addresses + masked weights for both voxels
    AW aw[2];
    #pragma unroll
    for (int c = 0; c < 2; ++c) {
        const int k = lane + (c << 6);
        int k0,k1; float tk;
        axis_interp(k, k0, k1, tk);
        float4 fl = lerp4(sF[w][k0], sF[w][k1], tk);
        float x = -1.f + s127 * (float)k + fl.x;
        float y = yb + fl.y;
        float z = zb + fl.z;
        aw[c] = make_aw(((x + 1.f) * (float)DIM - 1.f) * 0.5f,
                        ((y + 1.f) * (float)DIM - 1.f) * 0.5f,
                        ((z + 1.f) * (float)DIM - 1.f) * 0.5f);
    }

    // phase B: all 16 taps in flight before any accumulation
    float t0[8], t1[8];
    {
        const AW& s = aw[0];
        t0[0] = M[s.r0 + s.xa]; t0[1] = M[s.r0 + s.xb];
        t0[2] = M[s.r1 + s.xa]; t0[3] = M[s.r1 + s.xb];
        t0[4] = M[s.r2 + s.xa]; t0[5] = M[s.r2 + s.xb];
        t0[6] = M[s.r3 + s.xa]; t0[7] = M[s.r3 + s.xb];
    }
    {
        const AW& s = aw[1];
        t1[0] = M[s.r0 + s.xa]; t1[1] = M[s.r0 + s.xb];
        t1[2] = M[s.r1 + s.xa]; t1[3] = M[s.r1 + s.xb];
        t1[4] = M[s.r2 + s.xa]; t1[5] = M[s.r2 + s.xb];
        t1[6] = M[s.r3 + s.xa]; t1[7] = M[s.r3 + s.xb];
    }

    // phase C: accumulate + store
    float res[2];
    #pragma unroll
    for (int c = 0; c < 2; ++c) {
        const AW& s = aw[c];
        const float* tv = c ? t1 : t0;
        float w00 = s.wz0*s.wy0, w01 = s.wz0*s.wy1;
        float w10 = s.wz1*s.wy0, w11 = s.wz1*s.wy1;
        float r;
        r = tv[0] * (w00*s.wx0);
        r = fmaf(tv[1], w00*s.wx1, r);
        r = fmaf(tv[2], w01*s.wx0, r);
        r = fmaf(tv[3], w01*s.wx1, r);
        r = fmaf(tv[4], w10*s.wx0, r);
        r = fmaf(tv[5], w10*s.wx1, r);
        r = fmaf(tv[6], w11*s.wx0, r);
        r = fmaf(tv[7], w11*s.wx1, r);
        res[c] = r;
    }
    out[(line << 7) + lane]      = res[0];
    out[(line << 7) + lane + 64] = res[1];
}

extern "C" void kernel_launch(void* const* d_in, const int* in_sizes, int n_in,
                              void* d_out, int out_size, void* d_ws, size_t ws_size,
                              hipStream_t stream) {
    const float* mask   = (const float*)d_in[0];   // (2,1,128,128,128)
    const float* coords = (const float*)d_in[1];   // (2,1024,3)
    const float* offs   = (const float*)d_in[2];   // (2,1024,3)
    float* out = (float*)d_out;

    float4* coarse = (float4*)d_ws;                // NB*OPS3 float4

    dim3 g1(NP*NQ*NR, NB);                         // 500 x 2 blocks
    coarse_kernel<<<g1, 128, 0, stream>>>(coords, offs, coarse);

    warp_kernel<<<NB*DIM*DIM/4, 256, 0, stream>>>(mask, coarse, out);
}

// Round 8
// 97.977 us; speedup vs baseline: 1.1624x; 1.1497x over previous
//
#include <hip/hip_runtime.h>
#include <math.h>

#define NLM   1024      // landmarks per batch
#define NB    2         // batches
#define OPS   40        // coarse grid size per axis
#define DIM   128       // output volume size per axis
#define OPS3  (OPS*OPS*OPS)
#define DIM3  (DIM*DIM*DIM)

// coarse tile: 4(p) x 4(q) x 8(r) cells = 128 cells, 1 cell/thread
#define P_T 4
#define Q_T 4
#define R_T 8
#define NP  (OPS/P_T)    // 10
#define NQ  (OPS/Q_T)    // 10
#define NR  (OPS/R_T)    // 5
#define MARGIN 0.30f     // exp2(-288.5*0.09) ~ 2e-8 -> negligible truncation

// exp(-d2/ALPHA) = exp2(K2*d2), K2 = -1/(ALPHA*ln2); M2 = -2*K2
#define K2f  (-288.5390081777927f)
#define M2f  ( 577.0780163555854f)

// ws layout: coarse : float4[NB*OPS3] @ 0   (2,048,000 bytes)

__device__ __forceinline__ float fexp2(float x) {
#if __has_builtin(__builtin_amdgcn_exp2f)
    return __builtin_amdgcn_exp2f(x);
#else
    return exp2f(x);
#endif
}

// One block per 4x4x8 coarse tile (500 tiles x 2 batches), 128 threads.
__global__ __launch_bounds__(128)
void coarse_kernel(const float* __restrict__ coords, const float* __restrict__ offs,
                   float4* __restrict__ C) {
    __shared__ float4 sA[NLM];
    __shared__ float4 sV[NLM];
    __shared__ int sCnt;

    const int t = threadIdx.x;       // 0..127
    const int b = blockIdx.y;
    const int tile = blockIdx.x;     // 0..499
    const int tp = tile / (NQ*NR);
    const int tq = (tile / NR) % NQ;
    const int tr = tile % NR;

    const float step = 2.f / (OPS - 1);
    const float bx0 = -1.f + step * (tr*R_T)          - MARGIN;
    const float bx1 = -1.f + step * (tr*R_T + R_T-1)  + MARGIN;
    const float by0 = -1.f + step * (tq*Q_T)          - MARGIN;
    const float by1 = -1.f + step * (tq*Q_T + Q_T-1)  + MARGIN;
    const float bz0 = -1.f + step * (tp*P_T)          - MARGIN;
    const float bz1 = -1.f + step * (tp*P_T + P_T-1)  + MARGIN;

    if (t == 0) sCnt = 0;
    __syncthreads();

    for (int n = t; n < NLM; n += 128) {
        const float* cp = coords + (b*NLM + n)*3;
        const float* op = offs   + (b*NLM + n)*3;
        float ox = op[0], oy = op[1], oz = op[2];
        float cx = cp[0] + ox, cy = cp[1] + oy, cz = cp[2] + oz;
        if (cx >= bx0 && cx <= bx1 && cy >= by0 && cy <= by1 &&
            cz >= bz0 && cz <= bz1) {
            int idx = atomicAdd(&sCnt, 1);
            sA[idx] = make_float4(cx, cy, cz, K2f*(cx*cx + cy*cy + cz*cz));
            sV[idx] = make_float4(-ox, -oy, -oz, 0.f);
        }
    }
    __syncthreads();
    const int cnt = sCnt;

    const int lp = t >> 5;
    const int lq = (t >> 3) & 3;
    const int lr = t & 7;
    const float gx = -1.f + step * (tr*R_T + lr);
    const float gy = -1.f + step * (tq*Q_T + lq);
    const float gz = -1.f + step * (tp*P_T + lp);
    const float h  = K2f * (gx*gx + gy*gy + gz*gz);

    float aS = 0.f, aX = 0.f, aY = 0.f, aZ = 0.f;
    for (int n = 0; n < cnt; ++n) {
        float4 a = sA[n];            // LDS broadcast
        float4 v = sV[n];
        float u   = fmaf(gx, a.x, fmaf(gy, a.y, gz*a.z));
        float arg = fmaf(M2f, u, h + a.w);   // K2*||g-c||^2
        float e   = fexp2(arg);
        aS += e;
        aX = fmaf(e, v.x, aX);
        aY = fmaf(e, v.y, aY);
        aZ = fmaf(e, v.z, aZ);
    }

    const int p = tp*P_T + lp, q = tq*Q_T + lq, r = tr*R_T + lr;
    const float inv = 1.01f / (aS + 0.01f);
    C[b*OPS3 + (p*OPS + q)*OPS + r] = make_float4(aX*inv, aY*inv, aZ*inv, 0.f);
}

__device__ __forceinline__ void axis_interp(int t, int& a0, int& a1, float& w) {
    float c = fmaxf(0.3125f * (float)t - 0.34375f, 0.f);
    float f = floorf(c);
    a0 = (int)f;
    a1 = min(a0 + 1, OPS - 1);
    w = c - f;
}

__device__ __forceinline__ float4 lerp4(float4 a, float4 b, float t) {
    return make_float4(a.x + t*(b.x - a.x),
                       a.y + t*(b.y - a.y),
                       a.z + t*(b.z - a.z),
                       0.f);
}

// 4-byte-aligned float2 load (compiler may emit global_load_dwordx2 under
// HW unaligned-access mode; degrades to 2 dword loads otherwise).
typedef float vf2 __attribute__((ext_vector_type(2)));
struct __attribute__((packed, aligned(4))) P2 { vf2 v; };
__device__ __forceinline__ vf2 load2(const float* p) {
    return ((const P2*)p)->v;
}

// Per-voxel gather state: 4 wrapped row bases + pair base xs + pair weights
// (e0,e1) + row weights. 4 float2 taps instead of 8 float taps (halves the
// VMEM address count — the theory is TA/L1 address throughput is the
// bottleneck, all measured pipes being idle).
struct AW {
    int r0, r1, r2, r3, xs;
    float e0, e1, wy0, wy1, wz0, wz1;
};

__device__ __forceinline__ AW make_aw(float px, float py, float pz) {
    AW s;
    float xf = floorf(px), yf = floorf(py), zf = floorf(pz);
    int x0 = (int)xf, y0 = (int)yf, z0 = (int)zf;
    float ax = px - xf, ay = py - yf, az = pz - zf;

    float wx0 = ((unsigned)x0     < 128u) ? (1.f - ax) : 0.f;
    float wx1 = ((unsigned)(x0+1) < 128u) ? ax         : 0.f;
    s.wy0 = ((unsigned)y0     < 128u) ? (1.f - ay) : 0.f;
    s.wy1 = ((unsigned)(y0+1) < 128u) ? ay         : 0.f;
    s.wz0 = ((unsigned)z0     < 128u) ? (1.f - az) : 0.f;
    s.wz1 = ((unsigned)(z0+1) < 128u) ? az         : 0.f;

    s.xs = min(max(x0, 0), 126);           // pair [xs, xs+1] always in-bounds
    int d = x0 - s.xs;                     // 0 interior, -1 left edge, >=1 right
    s.e0 = (d == 0) ? wx0 : ((d == -1) ? wx1 : 0.f);
    s.e1 = (d == 0) ? wx1 : ((d ==  1) ? wx0 : 0.f);

    int ya = (y0 & 127) << 7, yb2 = ((y0+1) & 127) << 7;
    int za = (z0 & 127) << 14, zb2 = ((z0+1) & 127) << 14;
    s.r0 = za + ya;  s.r1 = za + yb2;
    s.r2 = zb2 + ya; s.r3 = zb2 + yb2;
    return s;
}

// 256-thread blocks = 4 waves; wave w handles one (b,i,j) k-line; each lane
// 2 voxels (k=lane, k=lane+64). XCD slab swizzle: slot g&7 owns a contiguous
// 32-i slab. Both voxels' 8 pair-taps issued before accumulation.
__global__ __launch_bounds__(256)
void warp_kernel(const float* __restrict__ mask, const float4* __restrict__ C,
                 float* __restrict__ out) {
    __shared__ float4 sF[4][OPS];    // per-wave k-line flow

    const int g = blockIdx.x;                        // 0..8191
    const int w = threadIdx.x >> 6;                  // wave 0..3
    const int lane = threadIdx.x & 63;
    const int line = ((g & 7) << 12) + ((g >> 3) << 2) + w;  // b*DIM^2+i*DIM+j
    const int j = line & (DIM-1);
    const int i = (line >> 7) & (DIM-1);
    const int b = line >> 14;

    int i0,i1,j0,j1; float ti,tj;
    axis_interp(i, i0, i1, ti);
    axis_interp(j, j0, j1, tj);

    const float4* Cb = C + b*OPS3;
    if (lane < OPS) {
        float4 c00 = Cb[(i0*OPS + j0)*OPS + lane];
        float4 c01 = Cb[(i0*OPS + j1)*OPS + lane];
        float4 c10 = Cb[(i1*OPS + j0)*OPS + lane];
        float4 c11 = Cb[(i1*OPS + j1)*OPS + lane];
        sF[w][lane] = lerp4(lerp4(c00, c01, tj), lerp4(c10, c11, tj), ti);
    }
    // no barrier: sF[w] is wave-private (produced & consumed in lockstep)

    const float* M = mask + b * DIM3;
    const float s127 = 2.f / (DIM - 1);
    const float yb = -1.f + s127 * (float)j;
    const float zb = -1.f + s127 * (float)i;

    // phase A: addresses + weights for both voxels
    AW aw[2];
    #pragma unroll
    for (int c = 0; c < 2; ++c) {
        const int k = lane + (c << 6);
        int k0,k1; float tk;
        axis_interp(k, k0, k1, tk);
        float4 fl = lerp4(sF[w][k0], sF[w][k1], tk);
        float x = -1.f + s127 * (float)k + fl.x;
        float y = yb + fl.y;
        float z = zb + fl.z;
        aw[c] = make_aw(((x + 1.f) * (float)DIM - 1.f) * 0.5f,
                        ((y + 1.f) * (float)DIM - 1.f) * 0.5f,
                        ((z + 1.f) * (float)DIM - 1.f) * 0.5f);
    }

    // phase B: all 8 pair-taps in flight before any accumulation
    vf2 t0[4], t1[4];
    {
        const AW& s = aw[0];
        t0[0] = load2(M + s.r0 + s.xs);
        t0[1] = load2(M + s.r1 + s.xs);
        t0[2] = load2(M + s.r2 + s.xs);
        t0[3] = load2(M + s.r3 + s.xs);
    }
    {
        const AW& s = aw[1];
        t1[0] = load2(M + s.r0 + s.xs);
        t1[1] = load2(M + s.r1 + s.xs);
        t1[2] = load2(M + s.r2 + s.xs);
        t1[3] = load2(M + s.r3 + s.xs);
    }

    // phase C: accumulate + store
    float res[2];
    #pragma unroll
    for (int c = 0; c < 2; ++c) {
        const AW& s = aw[c];
        const vf2* tv = c ? t1 : t0;
        float w00 = s.wz0*s.wy0, w01 = s.wz0*s.wy1;
        float w10 = s.wz1*s.wy0, w11 = s.wz1*s.wy1;
        float r;
        r = tv[0].x * (w00*s.e0);
        r = fmaf(tv[0].y, w00*s.e1, r);
        r = fmaf(tv[1].x, w01*s.e0, r);
        r = fmaf(tv[1].y, w01*s.e1, r);
        r = fmaf(tv[2].x, w10*s.e0, r);
        r = fmaf(tv[2].y, w10*s.e1, r);
        r = fmaf(tv[3].x, w11*s.e0, r);
        r = fmaf(tv[3].y, w11*s.e1, r);
        res[c] = r;
    }
    out[(line << 7) + lane]      = res[0];
    out[(line << 7) + lane + 64] = res[1];
}

extern "C" void kernel_launch(void* const* d_in, const int* in_sizes, int n_in,
                              void* d_out, int out_size, void* d_ws, size_t ws_size,
                              hipStream_t stream) {
    const float* mask   = (const float*)d_in[0];   // (2,1,128,128,128)
    const float* coords = (const float*)d_in[1];   // (2,1024,3)
    const float* offs   = (const float*)d_in[2];   // (2,1024,3)
    float* out = (float*)d_out;

    float4* coarse = (float4*)d_ws;                // NB*OPS3 float4

    dim3 g1(NP*NQ*NR, NB);                         // 500 x 2 blocks
    coarse_kernel<<<g1, 128, 0, stream>>>(coords, offs, coarse);

    warp_kernel<<<NB*DIM*DIM/4, 256, 0, stream>>>(mask, coarse, out);
}